// Round 1
// baseline (2016.810 us; speedup 1.0000x reference)
//
#include <hip/hip_runtime.h>
#include <hip/hip_bf16.h>

#define TT 2048
#define BB 512
#define HH 64

__device__ __forceinline__ float frcp(float x){ return __builtin_amdgcn_rcpf(x); }
__device__ __forceinline__ float fsig(float a){ return frcp(1.0f + __expf(-a)); }
__device__ __forceinline__ float ftanh(float a){ return 1.0f - 2.0f*frcp(__expf(2.0f*a)+1.0f); }
__device__ __forceinline__ float bcast(float v, int lane){
  return __uint_as_float((unsigned)__builtin_amdgcn_readlane((int)__float_as_uint(v), lane));
}

// One block = one batch row. 2 waves: wave0 owns gate quads {i,f}, wave1 owns {g,o}.
// Lane j owns h_j, c_j (redundantly in both waves). h broadcast via readlane->SGPR,
// so the 128 FMAs/lane/step are v_fmac_f32 with an SGPR h-operand and VGPR weights.
__global__ __launch_bounds__(128, 1) void lstm_fwd_kernel(
    const float* __restrict__ x, const float* __restrict__ Wih,
    const float* __restrict__ Whh, const float* __restrict__ bih,
    const float* __restrict__ bhh, float* __restrict__ hout)
{
  const int b   = blockIdx.x;
  const int tid = threadIdx.x;
  const int wv  = tid >> 6;      // 0 or 1
  const int j   = tid & 63;      // lane index == hidden index
  const int gA  = (wv*2 + 0)*HH + j;   // wave0: i (q0), wave1: g (q2)
  const int gB  = (wv*2 + 1)*HH + j;   // wave0: f (q1), wave1: o (q3)

  // recurrent weights into registers (64 + 64 VGPRs)
  float wA[HH], wB[HH];
  const float4* wArow = reinterpret_cast<const float4*>(Whh + gA*HH);
  const float4* wBrow = reinterpret_cast<const float4*>(Whh + gB*HH);
  #pragma unroll
  for (int k = 0; k < HH/4; k++){
    float4 a = wArow[k]; float4 bq = wBrow[k];
    wA[4*k+0]=a.x;  wA[4*k+1]=a.y;  wA[4*k+2]=a.z;  wA[4*k+3]=a.w;
    wB[4*k+0]=bq.x; wB[4*k+1]=bq.y; wB[4*k+2]=bq.z; wB[4*k+3]=bq.w;
  }
  float wiA[7], wiB[7];
  #pragma unroll
  for (int k = 0; k < 7; k++){ wiA[k]=Wih[gA*7+k]; wiB[k]=Wih[gB*7+k]; }
  const float biasA = bih[gA] + bhh[gA];
  const float biasB = bih[gB] + bhh[gB];

  // tiny cross-wave exchange buffers, double-buffered on t parity
  __shared__ float exA[2][HH*2];
  __shared__ float exB[2][HH*2];

  float h = 0.0f, c = 0.0f;
  const float* xr = x + (size_t)b*TT*7;
  float xc[7];
  #pragma unroll
  for (int k = 0; k < 7; k++) xc[k] = xr[k];

  #pragma unroll 1
  for (int t = 0; t < TT; t++){
    // prefetch next step's input (wave-uniform -> s_load; latency hidden by dot)
    const float* xp1 = xr + (size_t)((t+1 < TT) ? (t+1) : t)*7;
    float xn[7];
    #pragma unroll
    for (int k = 0; k < 7; k++) xn[k] = xp1[k];

    float a0=biasA, a1=0.f, a2=0.f, a3=0.f;
    float b0=biasB, b1=0.f, b2=0.f, b3=0.f;
    #pragma unroll
    for (int k = 0; k < 7; k++){ a0 += xc[k]*wiA[k]; b0 += xc[k]*wiB[k]; }

    #pragma unroll
    for (int k = 0; k < HH; k += 4){
      float h0 = bcast(h, k+0), h1 = bcast(h, k+1);
      float h2 = bcast(h, k+2), h3 = bcast(h, k+3);
      a0 += h0*wA[k+0];  b0 += h0*wB[k+0];
      a1 += h1*wA[k+1];  b1 += h1*wB[k+1];
      a2 += h2*wA[k+2];  b2 += h2*wB[k+2];
      a3 += h3*wA[k+3];  b3 += h3*wB[k+3];
    }
    const float accA = (a0+a1)+(a2+a3);
    const float accB = (b0+b1)+(b2+b3);

    float vA, vB;
    if (wv == 0){ vA = fsig(accA);  vB = fsig(accB); }   // i, f
    else        { vA = ftanh(accA); vB = fsig(accB); }   // g, o

    const int par = t & 1;
    if (wv == 0){ exA[par][2*j]=vA; exA[par][2*j+1]=vB; }
    else        { exB[par][2*j]=vA; exB[par][2*j+1]=vB; }
    __syncthreads();

    float iv, fv, gv, ov;
    if (wv == 0){ iv=vA; fv=vB; gv=exB[par][2*j]; ov=exB[par][2*j+1]; }
    else        { gv=vA; ov=vB; iv=exA[par][2*j]; fv=exA[par][2*j+1]; }

    c = fv*c + iv*gv;
    h = ov*ftanh(c);

    #pragma unroll
    for (int k = 0; k < 7; k++) xc[k] = xn[k];
  }
  if (wv == 0) hout[b*HH + j] = h;
}

// Backward direction contributes only ONE step (scan reverse=True: output at t=T-1
// is the first reverse step from zero state => W_hh_b unused, c = i*g).
// Fused with the final linear layer.
__global__ __launch_bounds__(64, 1) void lstm_bwd_lin_kernel(
    const float* __restrict__ x,   const float* __restrict__ Wib,
    const float* __restrict__ bib, const float* __restrict__ bhb,
    const float* __restrict__ Wlin,const float* __restrict__ blin,
    const float* __restrict__ hf,  float* __restrict__ out)
{
  const int b = blockIdx.x;
  const int j = threadIdx.x;  // 0..63
  const float* xt = x + ((size_t)b*TT + (TT-1))*7;
  float xv[7];
  #pragma unroll
  for (int k = 0; k < 7; k++) xv[k] = xt[k];

  float g4[4];
  #pragma unroll
  for (int q = 0; q < 4; q++){
    const int g = q*HH + j;
    float a = bib[g] + bhb[g];
    #pragma unroll
    for (int k = 0; k < 7; k++) a += xv[k]*Wib[g*7+k];
    g4[q] = a;
  }
  const float iv = fsig(g4[0]);
  const float gv = ftanh(g4[2]);
  const float ov = fsig(g4[3]);
  const float cc = iv*gv;          // f * c0 = 0
  const float hb = ov*ftanh(cc);
  const float hfv = hf[b*HH + j];

  float s[3];
  #pragma unroll
  for (int o = 0; o < 3; o++)
    s[o] = hfv*Wlin[o*128 + j] + hb*Wlin[o*128 + 64 + j];

  #pragma unroll
  for (int o = 0; o < 3; o++){
    float v = s[o];
    #pragma unroll
    for (int m = 32; m >= 1; m >>= 1) v += __shfl_xor(v, m, 64);
    s[o] = v;
  }
  if (j == 0){
    out[b*3+0] = s[0] + blin[0];
    out[b*3+1] = s[1] + blin[1];
    out[b*3+2] = s[2] + blin[2];
  }
}

extern "C" void kernel_launch(void* const* d_in, const int* in_sizes, int n_in,
                              void* d_out, int out_size, void* d_ws, size_t ws_size,
                              hipStream_t stream)
{
  const float* x    = (const float*)d_in[0];
  const float* Wihf = (const float*)d_in[1];
  const float* Whhf = (const float*)d_in[2];
  const float* bihf = (const float*)d_in[3];
  const float* bhhf = (const float*)d_in[4];
  const float* Wihb = (const float*)d_in[5];
  // d_in[6] (W_hh_b) is mathematically unused: backward state starts at zero
  const float* bibb = (const float*)d_in[7];
  const float* bhbb = (const float*)d_in[8];
  const float* Wlin = (const float*)d_in[9];
  const float* blin = (const float*)d_in[10];
  float* out = (float*)d_out;
  float* hf  = (float*)d_ws;   // [512,64] fp32 scratch

  lstm_fwd_kernel<<<BB, 128, 0, stream>>>(x, Wihf, Whhf, bihf, bhhf, hf);
  lstm_bwd_lin_kernel<<<BB, 64, 0, stream>>>(x, Wihb, bibb, bhbb, Wlin, blin, hf, out);
}

// Round 2
// 1438.356 us; speedup vs baseline: 1.4022x; 1.4022x over previous
//
#include <hip/hip_runtime.h>
#include <hip/hip_bf16.h>

#define TT 2048
#define BB 512
#define HH 64

__device__ __forceinline__ float frcp(float x){ return __builtin_amdgcn_rcpf(x); }
__device__ __forceinline__ float fsig(float a){ return frcp(1.0f + __expf(-a)); }
__device__ __forceinline__ float ftanh(float a){ return 1.0f - 2.0f*frcp(__expf(2.0f*a)+1.0f); }
__device__ __forceinline__ float bcast(float v, int lane){
  return __uint_as_float((unsigned)__builtin_amdgcn_readlane((int)__float_as_uint(v), lane));
}

// One block = one batch row. 4 waves; wave q owns gate quad q (0:i 1:f 2:g 3:o).
// Lane j computes gate[q*64+j]: dot(Whh_row, h) with h broadcast lane->SGPR via
// readlane, weights held in 64 VGPRs/lane (float4 w4[16]). One barrier/step,
// parity double-buffered LDS exchange of the 4 post-activation gate vectors.
__global__ __launch_bounds__(256, 1) void lstm_fwd_kernel(
    const float* __restrict__ x, const float* __restrict__ Wih,
    const float* __restrict__ Whh, const float* __restrict__ bih,
    const float* __restrict__ bhh, float* __restrict__ hout)
{
  const int b   = blockIdx.x;
  const int tid = threadIdx.x;
  const int q   = tid >> 6;      // gate quad
  const int j   = tid & 63;      // hidden index == lane
  const int g   = q*HH + j;

  // recurrent weight row -> 64 VGPRs
  float4 w4[16];
  const float4* wrow = reinterpret_cast<const float4*>(Whh + (size_t)g*HH);
  #pragma unroll
  for (int k = 0; k < 16; k++) w4[k] = wrow[k];

  float wi[7];
  #pragma unroll
  for (int k = 0; k < 7; k++) wi[k] = Wih[g*7+k];
  const float bias = bih[g] + bhh[g];

  __shared__ float ex[2][4][HH];   // parity x gate-quad x hidden

  float h = 0.0f, c = 0.0f;
  const float* xr = x + (size_t)b*TT*7;
  float xc[7];
  #pragma unroll
  for (int k = 0; k < 7; k++) xc[k] = xr[k];

  #pragma unroll 1
  for (int t = 0; t < TT; t++){
    // prefetch next step's x (wave-uniform -> scalar loads; hidden by the dot)
    const float* xp1 = xr + (size_t)((t+1 < TT) ? (t+1) : t)*7;
    float xn[7];
    #pragma unroll
    for (int k = 0; k < 7; k++) xn[k] = xp1[k];

    float a0 = bias, a1 = 0.f, a2 = 0.f, a3 = 0.f;
    #pragma unroll
    for (int k = 0; k < 7; k++) a0 += xc[k]*wi[k];

    #pragma unroll
    for (int k = 0; k < 16; k++){
      const float h0 = bcast(h, 4*k+0), h1 = bcast(h, 4*k+1);
      const float h2 = bcast(h, 4*k+2), h3 = bcast(h, 4*k+3);
      a0 += h0*w4[k].x;
      a1 += h1*w4[k].y;
      a2 += h2*w4[k].z;
      a3 += h3*w4[k].w;
    }
    const float acc = (a0+a1)+(a2+a3);

    const float v = (q == 2) ? ftanh(acc) : fsig(acc);

    const int par = t & 1;
    ex[par][q][j] = v;
    __syncthreads();

    const float iv = ex[par][0][j];
    const float fv = ex[par][1][j];
    const float gv = ex[par][2][j];
    const float ov = ex[par][3][j];

    c = fv*c + iv*gv;
    h = ov*ftanh(c);

    #pragma unroll
    for (int k = 0; k < 7; k++) xc[k] = xn[k];
  }
  if (q == 0) hout[b*HH + j] = h;
}

// Backward direction contributes only ONE step (scan reverse=True: output at
// t=T-1 is the first reverse step from zero state => W_hh_b unused, c = i*g).
// Fused with the final linear layer.
__global__ __launch_bounds__(64, 1) void lstm_bwd_lin_kernel(
    const float* __restrict__ x,   const float* __restrict__ Wib,
    const float* __restrict__ bib, const float* __restrict__ bhb,
    const float* __restrict__ Wlin,const float* __restrict__ blin,
    const float* __restrict__ hf,  float* __restrict__ out)
{
  const int b = blockIdx.x;
  const int j = threadIdx.x;  // 0..63
  const float* xt = x + ((size_t)b*TT + (TT-1))*7;
  float xv[7];
  #pragma unroll
  for (int k = 0; k < 7; k++) xv[k] = xt[k];

  float g4[4];
  #pragma unroll
  for (int qq = 0; qq < 4; qq++){
    const int g = qq*HH + j;
    float a = bib[g] + bhb[g];
    #pragma unroll
    for (int k = 0; k < 7; k++) a += xv[k]*Wib[g*7+k];
    g4[qq] = a;
  }
  const float iv = fsig(g4[0]);
  const float gv = ftanh(g4[2]);
  const float ov = fsig(g4[3]);
  const float cc = iv*gv;          // f * c0 = 0
  const float hb = ov*ftanh(cc);
  const float hfv = hf[b*HH + j];

  float s[3];
  #pragma unroll
  for (int o = 0; o < 3; o++)
    s[o] = hfv*Wlin[o*128 + j] + hb*Wlin[o*128 + 64 + j];

  #pragma unroll
  for (int o = 0; o < 3; o++){
    float v = s[o];
    #pragma unroll
    for (int m = 32; m >= 1; m >>= 1) v += __shfl_xor(v, m, 64);
    s[o] = v;
  }
  if (j == 0){
    out[b*3+0] = s[0] + blin[0];
    out[b*3+1] = s[1] + blin[1];
    out[b*3+2] = s[2] + blin[2];
  }
}

extern "C" void kernel_launch(void* const* d_in, const int* in_sizes, int n_in,
                              void* d_out, int out_size, void* d_ws, size_t ws_size,
                              hipStream_t stream)
{
  const float* x    = (const float*)d_in[0];
  const float* Wihf = (const float*)d_in[1];
  const float* Whhf = (const float*)d_in[2];
  const float* bihf = (const float*)d_in[3];
  const float* bhhf = (const float*)d_in[4];
  const float* Wihb = (const float*)d_in[5];
  // d_in[6] (W_hh_b) is mathematically unused: backward state starts at zero
  const float* bibb = (const float*)d_in[7];
  const float* bhbb = (const float*)d_in[8];
  const float* Wlin = (const float*)d_in[9];
  const float* blin = (const float*)d_in[10];
  float* out = (float*)d_out;
  float* hf  = (float*)d_ws;   // [512,64] fp32 scratch

  lstm_fwd_kernel<<<BB, 256, 0, stream>>>(x, Wihf, Whhf, bihf, bhhf, hf);
  lstm_bwd_lin_kernel<<<BB, 64, 0, stream>>>(x, Wihb, bibb, bhbb, Wlin, blin, hf, out);
}